// Round 3
// baseline (242.687 us; speedup 1.0000x reference)
//
#include <hip/hip_runtime.h>
#include <hip/hip_cooperative_groups.h>

namespace cg = cooperative_groups;

#define B 8
#define N 8192
#define M 2048
#define NITER 4
#define BASE_ALPHA 0.1f

#define NSPLIT 16              // j-splits per block (inside block)
#define JS (M / NSPLIT)        // 128 y's per split
#define PPB 256                // points owned per block
#define PT 8                   // points per scan-thread
#define NPT 32                 // point-lanes (PPB / PT)
#define NTHR (NPT * NSPLIT)    // 512 threads = 8 waves
#define NBLK (B * N / PPB)     // 256 blocks = 1 per CU

// ws: maxb uint[NITER*B] @0 (128 B), zeroed via hipMemsetAsync each call.

__device__ __forceinline__ unsigned int ord32(float t) {
    unsigned int u = __float_as_uint(t);
    return u ^ ((unsigned int)((int)u >> 31) | 0x80000000u);   // float order -> uint order
}
__device__ __forceinline__ float dec32(unsigned int h) {
    return __uint_as_float((h & 0x80000000u) ? (h ^ 0x80000000u) : ~h);
}

__global__ __launch_bounds__(NTHR, 1) void refine_all(const float* __restrict__ pred,
                                                      const float* __restrict__ partial,
                                                      unsigned int* __restrict__ maxb,
                                                      float* __restrict__ out) {
    cg::grid_group grid = cg::this_grid();
    __shared__ float4 tile[M];                          // 32 KB  {y0,y1,y2,|y|^2}
    __shared__ unsigned long long lkeys[NSPLIT / 2][PPB]; // 16 KB
    __shared__ float4 lpos[PPB];                        // 4 KB   {x,y,z,|r|^2}
    __shared__ float redbuf[4];

    const int tid = threadIdx.x;
    const int b = blockIdx.x >> 5;                      // 32 blocks per batch
    const int gp0 = b * N + (blockIdx.x & 31) * PPB;    // first global point of block

    // Build y-tile once (same arithmetic as reference's y2 term).
    const float* pa = partial + b * M * 3;
    for (int i = tid; i < M; i += NTHR) {
        float y0 = pa[i * 3 + 0], y1 = pa[i * 3 + 1], y2 = pa[i * 3 + 2];
        tile[i] = make_float4(y0, y1, y2, y0 * y0 + y1 * y1 + y2 * y2);
    }
    // Owner threads (tid < PPB) hold point state in registers across iterations.
    float px = 0.f, py = 0.f, pz = 0.f, pw = 0.f;
    if (tid < PPB) {
        const float* pp = pred + (unsigned long long)(gp0 + tid) * 3;
        px = pp[0]; py = pp[1]; pz = pp[2];
        pw = px * px + py * py + pz * pz;
        lpos[tid] = make_float4(px, py, pz, pw);
    }
    __syncthreads();

    const int split = tid >> 5;                         // 0..15 (uniform per half-wave)
    const int pt = tid & 31;                            // 0..31
    const float4* __restrict__ qs = tile + split * JS;

    for (int iter = 0; iter < NITER; ++iter) {
        // ---- scan: each thread = 8 points x 128 y's ----
        float nx0[PT], nx1[PT], nx2[PT];
        #pragma unroll
        for (int k = 0; k < PT; ++k) {
            float4 r = lpos[pt + k * NPT];
            nx0[k] = -2.0f * r.x; nx1[k] = -2.0f * r.y; nx2[k] = -2.0f * r.z;
        }
        float vb[PT]; int ib[PT];
        #pragma unroll
        for (int k = 0; k < PT; ++k) { vb[k] = 3.402823466e+38f; ib[k] = 0; }

        #pragma unroll 2
        for (int j = 0; j < JS; ++j) {
            float4 q = qs[j];                           // ds_read_b128, half-wave broadcast
            #pragma unroll
            for (int k = 0; k < PT; ++k) {
                float t = fmaf(nx0[k], q.x, fmaf(nx1[k], q.y, fmaf(nx2[k], q.z, q.w)));
                if (t < vb[k]) { vb[k] = t; ib[k] = j; }  // strict < keeps earliest j
            }
        }

        // ---- merge split-pairs within wave (lane^32 = same pt, split^1), then to LDS ----
        #pragma unroll
        for (int k = 0; k < PT; ++k) {
            unsigned long long key =
                (((unsigned long long)ord32(vb[k])) << 32) | (unsigned int)(split * JS + ib[k]);
            unsigned int hi = (unsigned int)(key >> 32), lo = (unsigned int)key;
            unsigned int ohi = __shfl_xor(hi, 32);
            unsigned int olo = __shfl_xor(lo, 32);
            unsigned long long okey = (((unsigned long long)ohi) << 32) | olo;
            if (okey < key) key = okey;                 // u64 min == (t, then j) min: exact tie-break
            if ((tid & 32) == 0) lkeys[split >> 1][pt + (k << 5)] = key;
        }
        __syncthreads();

        // ---- owners: final argmin over 8 key rows, per-batch max ----
        float md = 0.f; int idx = 0;
        if (tid < PPB) {
            unsigned long long best = lkeys[0][tid];
            #pragma unroll
            for (int s = 1; s < NSPLIT / 2; ++s) {
                unsigned long long c = lkeys[s][tid];
                if (c < best) best = c;
            }
            idx = (int)(unsigned int)(best & 0xFFFFFFFFull);
            float t = dec32((unsigned int)(best >> 32));
            md = sqrtf(fmaxf(pw + t, 0.0f));            // |r|^2 + (|y|^2 - 2 r.y)
            float wm = md;
            for (int o = 32; o > 0; o >>= 1) wm = fmaxf(wm, __shfl_down(wm, o));
            if ((tid & 63) == 0) redbuf[tid >> 6] = wm;
        }
        __syncthreads();
        if (tid == 0) {
            float bm = fmaxf(fmaxf(redbuf[0], redbuf[1]), fmaxf(redbuf[2], redbuf[3]));
            atomicMax(&maxb[iter * B + b], __float_as_uint(bm));   // md >= 0: uint order == float order
        }
        grid.sync();                                    // max finalized device-wide

        // ---- owners: apply update ----
        if (tid < PPB) {
            float mx = __uint_as_float(((volatile unsigned int*)maxb)[iter * B + b]);
            float inv = 1.0f / (mx + 1e-6f);
            float alpha = BASE_ALPHA * (2.0f - md * inv);
            float4 nr = tile[idx];
            px = fmaf(alpha, nr.x - px, px);
            py = fmaf(alpha, nr.y - py, py);
            pz = fmaf(alpha, nr.z - pz, pz);
            if (iter == NITER - 1) {
                float* po = out + (unsigned long long)(gp0 + tid) * 3;
                po[0] = px; po[1] = py; po[2] = pz;
            } else {
                pw = px * px + py * py + pz * pz;
                lpos[tid] = make_float4(px, py, pz, pw);
            }
        }
        __syncthreads();                                // lpos ready for next scan
    }
}

extern "C" void kernel_launch(void* const* d_in, const int* in_sizes, int n_in,
                              void* d_out, int out_size, void* d_ws, size_t ws_size,
                              hipStream_t stream) {
    const float* pred = (const float*)d_in[0];
    const float* partial = (const float*)d_in[1];
    unsigned int* maxb = (unsigned int*)d_ws;
    float* out = (float*)d_out;

    hipMemsetAsync(maxb, 0, NITER * B * sizeof(unsigned int), stream);

    void* args[] = {(void*)&pred, (void*)&partial, (void*)&maxb, (void*)&out};
    hipLaunchCooperativeKernel((const void*)refine_all, dim3(NBLK), dim3(NTHR),
                               args, 0, stream);
}

// Round 5
// 227.052 us; speedup vs baseline: 1.0689x; 1.0689x over previous
//
#include <hip/hip_runtime.h>

#define B 8
#define N 8192
#define M 2048
#define NITER 4
#define BASE_ALPHA 0.1f

#define NTHR 1024              // threads per block = 16 waves (4 waves/SIMD)
#define NPT 32                 // point-lanes per split
#define NSPLIT 32              // j-splits per block
#define JS (M / NSPLIT)        // 64 y's per split
#define PT 8                   // points per thread
#define PPB (NPT * PT)         // 256 points per block
#define NBLK (B * N / PPB)     // 256 blocks = 1 per CU (unconditionally co-resident)
#define BPB (NBLK / B)         // 32 blocks per batch

// ws: maxv uint[NITER*B] @0, cnt uint[NITER*B] @128 — 256 B, memsetAsync(0) per call.

__device__ __forceinline__ unsigned int ord32(float t) {
    unsigned int u = __float_as_uint(t);
    return u ^ ((unsigned int)((int)u >> 31) | 0x80000000u);   // float order -> uint order
}
__device__ __forceinline__ float dec32(unsigned int h) {
    return __uint_as_float((h & 0x80000000u) ? (h ^ 0x80000000u) : ~h);
}

__global__ __launch_bounds__(NTHR, 4) void refine_all(const float* __restrict__ pred,
                                                      const float* __restrict__ partial,
                                                      unsigned int* __restrict__ maxv,
                                                      unsigned int* __restrict__ cnt,
                                                      float* __restrict__ out) {
    __shared__ float4 tile[M + 4];                    // {y0,y1,y2,|y|^2}; pad for 1-ahead prefetch
    __shared__ unsigned long long lkeys[16][PPB];     // 32 KB: one row per wave
    __shared__ float4 lpos[PPB];                      // 4 KB {x,y,z,|r|^2}
    __shared__ float redbuf[8];                       // [0..3] owner-wave maxes; [4] broadcast mx

    const int tid = threadIdx.x;
    const int b = blockIdx.x >> 5;                    // 32 blocks per batch
    const int gp0 = b * N + (blockIdx.x & 31) * PPB;

    // Build y-tile once (matches reference y2 term).
    const float* pa = partial + b * M * 3;
    for (int i = tid; i < M; i += NTHR) {
        float y0 = pa[i * 3 + 0], y1 = pa[i * 3 + 1], y2 = pa[i * 3 + 2];
        tile[i] = make_float4(y0, y1, y2, y0 * y0 + y1 * y1 + y2 * y2);
    }
    if (tid < PPB) {
        const float* pp = pred + (unsigned long long)(gp0 + tid) * 3;
        float x = pp[0], y = pp[1], z = pp[2];
        lpos[tid] = make_float4(x, y, z, x * x + y * y + z * z);
    }
    __syncthreads();

    const int split = tid >> 5;                       // 0..31, uniform per half-wave
    const int pt = tid & 31;                          // 0..31
    const int wave = tid >> 6;                        // 0..15
    const float4* __restrict__ qs = tile + split * JS;

    for (int iter = 0; iter < NITER; ++iter) {
        // ---- scan: 8 points x 64 y's per thread ----
        float nx0[PT], nx1[PT], nx2[PT];
        #pragma unroll
        for (int k = 0; k < PT; ++k) {
            float4 r = lpos[pt + k * NPT];
            nx0[k] = -2.0f * r.x; nx1[k] = -2.0f * r.y; nx2[k] = -2.0f * r.z;
        }
        float vb[PT]; int ib[PT];
        #pragma unroll
        for (int k = 0; k < PT; ++k) { vb[k] = 3.402823466e+38f; ib[k] = 0; }

        float4 q = qs[0];
        #pragma unroll 2
        for (int j = 0; j < JS; ++j) {
            float4 qn = qs[j + 1];                    // 1-ahead prefetch (pad makes j=JS-1 safe)
            #pragma unroll
            for (int k = 0; k < PT; ++k) {
                float t = fmaf(nx0[k], q.x, fmaf(nx1[k], q.y, fmaf(nx2[k], q.z, q.w)));
                if (t < vb[k]) { vb[k] = t; ib[k] = j; }   // strict < keeps earliest j
            }
            q = qn;
        }

        // ---- merge the wave's two splits (lane^32: same pt, split^1), write per-wave row ----
        #pragma unroll
        for (int k = 0; k < PT; ++k) {
            unsigned int hi = ord32(vb[k]);
            unsigned int lo = (unsigned int)(split * JS + ib[k]);
            unsigned int ohi = __shfl_xor(hi, 32), olo = __shfl_xor(lo, 32);
            if (ohi < hi || (ohi == hi && olo < lo)) { hi = ohi; lo = olo; }   // (t, j) lex min
            if ((tid & 32) == 0)
                lkeys[wave][pt + k * NPT] = (((unsigned long long)hi) << 32) | lo;
        }
        __syncthreads();

        // ---- owners (tid<256 = waves 0..3): final min over 16 wave-rows, batch max ----
        float md = 0.0f; int idx = 0; float4 f4 = make_float4(0, 0, 0, 0);
        if (tid < PPB) {
            unsigned long long best = lkeys[0][tid];
            #pragma unroll
            for (int r = 1; r < 16; ++r) {
                unsigned long long c = lkeys[r][tid];
                if (c < best) best = c;
            }
            idx = (int)(unsigned int)(best & 0xFFFFFFFFull);
            float t = dec32((unsigned int)(best >> 32));
            f4 = lpos[tid];
            md = sqrtf(fmaxf(f4.w + t, 0.0f));        // |r|^2 + (|y|^2 - 2 r.y)
            float wm = md;
            for (int o = 32; o > 0; o >>= 1) wm = fmaxf(wm, __shfl_down(wm, o));
            if ((tid & 63) == 0) redbuf[tid >> 6] = wm;
        }
        __syncthreads();

        // ---- per-batch barrier over 32 blocks: atomicMax + count, one spinner ----
        if (tid == 0) {
            float bm = fmaxf(fmaxf(redbuf[0], redbuf[1]), fmaxf(redbuf[2], redbuf[3]));
            unsigned int* mv = &maxv[iter * B + b];
            unsigned int* cv = &cnt[iter * B + b];
            __hip_atomic_fetch_max(mv, __float_as_uint(bm),
                                   __ATOMIC_SEQ_CST, __HIP_MEMORY_SCOPE_AGENT);
            __hip_atomic_fetch_add(cv, 1u, __ATOMIC_SEQ_CST, __HIP_MEMORY_SCOPE_AGENT);
            while (__hip_atomic_load(cv, __ATOMIC_ACQUIRE, __HIP_MEMORY_SCOPE_AGENT) < BPB)
                __builtin_amdgcn_s_sleep(2);
            unsigned int mu = __hip_atomic_load(mv, __ATOMIC_ACQUIRE, __HIP_MEMORY_SCOPE_AGENT);
            redbuf[4] = __uint_as_float(mu);
        }
        __syncthreads();

        // ---- owners: apply update ----
        if (tid < PPB) {
            float mx = redbuf[4];
            float inv = 1.0f / (mx + 1e-6f);
            float alpha = BASE_ALPHA * (2.0f - md * inv);
            float4 nr = tile[idx];
            float rx = fmaf(alpha, nr.x - f4.x, f4.x);
            float ry = fmaf(alpha, nr.y - f4.y, f4.y);
            float rz = fmaf(alpha, nr.z - f4.z, f4.z);
            if (iter == NITER - 1) {
                float* po = out + (unsigned long long)(gp0 + tid) * 3;
                po[0] = rx; po[1] = ry; po[2] = rz;
            } else {
                lpos[tid] = make_float4(rx, ry, rz, rx * rx + ry * ry + rz * rz);
            }
        }
        __syncthreads();
    }
}

extern "C" void kernel_launch(void* const* d_in, const int* in_sizes, int n_in,
                              void* d_out, int out_size, void* d_ws, size_t ws_size,
                              hipStream_t stream) {
    const float* pred = (const float*)d_in[0];
    const float* partial = (const float*)d_in[1];
    unsigned int* maxv = (unsigned int*)d_ws;
    unsigned int* cntv = maxv + NITER * B;
    float* out = (float*)d_out;

    hipMemsetAsync(d_ws, 0, 2 * NITER * B * sizeof(unsigned int), stream);

    void* args[] = {(void*)&pred, (void*)&partial, (void*)&maxv, (void*)&cntv, (void*)&out};
    hipLaunchCooperativeKernel((const void*)refine_all, dim3(NBLK), dim3(NTHR),
                               args, 0, stream);
}